// Round 8
// baseline (66.445 us; speedup 1.0000x reference)
//
#include <hip/hip_runtime.h>

#define NN 177
#define NEG 0.2f
#define QR 45                 // dst rows per quarter (last quarter 42)
#define QSLOTS (QR * NN)      // 7965
#define SL 8064               // padded partial slice
#define NCHUNK 128
#define EBLOCKS (NCHUNK * 4)  // 512
#define ETH 512

// workspace layout (floats)
#define G_OFF    384
#define PART_OFF 23040        // 512 slices of SL (~16.5 MB)

// Kernel A: self-contained edge pass.
//  - u = W@att0, v = W@att1 (per-block, float4 + wave shuffle reduce)  [coalesced]
//  - ai[n] = x[n]·u, aj[n] = x[n]·v : ONE WAVE PER ROW, lanes stride the row
//    (coalesced; the R7 thread-per-row version was 64B-per-4B uncoalesced)
//  - blocks 0..176 also emit G row n = (x[n]@W)@eu
//  - LDS-private W-quarter edge accumulation, partial flush
__global__ __launch_bounds__(ETH)
void k_edgeA(const float* __restrict__ x, const float* __restrict__ ea,
             const float* __restrict__ w, const float* __restrict__ att,
             const float* __restrict__ eu, const int* __restrict__ ei,
             float* __restrict__ ws, int E, int CH) {
    __shared__ float Wl[QSLOTS];
    __shared__ float ajl[NN], ail[NN], Mq[QR], llast[QR];
    __shared__ float uvec[128], vvec[128], atl[257];
    const int tid = threadIdx.x;
    const int bid = blockIdx.x;

    for (int i = tid; i < 257; i += ETH) atl[i] = att[i];
    __syncthreads();

    // ---- u = W@att0, v = W@att1 (coalesced float4 + shuffle) ----
#pragma unroll
    for (int i = 0; i < 8; ++i) {
        int flat = i * 2048 + tid * 4;
        int k = flat >> 7, c = flat & 127;
        float4 wv = *(const float4*)(w + flat);
        float pu = wv.x*atl[c]     + wv.y*atl[c+1]     + wv.z*atl[c+2]     + wv.w*atl[c+3];
        float pv = wv.x*atl[128+c] + wv.y*atl[128+c+1] + wv.z*atl[128+c+2] + wv.w*atl[128+c+3];
#pragma unroll
        for (int m = 1; m <= 16; m <<= 1) {
            pu += __shfl_xor(pu, m);
            pv += __shfl_xor(pv, m);
        }
        if ((tid & 31) == 0) { uvec[k] = pu; vvec[k] = pv; }
    }
    __syncthreads();

    // ---- ai, aj: wave-per-row coalesced dots ----
    {
        const int wid = tid >> 6, lane = tid & 63;
        for (int r = wid; r < NN; r += 8) {
            const float* xr = x + r * 128;
            float x0 = xr[lane], x1 = xr[64 + lane];
            float pa = x0 * uvec[lane] + x1 * uvec[64 + lane];
            float pb = x0 * vvec[lane] + x1 * vvec[64 + lane];
#pragma unroll
            for (int m = 1; m < 64; m <<= 1) {
                pa += __shfl_xor(pa, m);
                pb += __shfl_xor(pb, m);
            }
            if (lane == 0) { ail[r] = pa; ajl[r] = pb; }
        }
    }
    __syncthreads();

    // ---- blocks 0..176: h row + G row ----
    if (bid < NN) {
        float* ph = Wl + 1024;
        float* xl = Wl + 1536;
        float* hl = Wl + 1664;
        if (tid < 128) xl[tid] = x[bid * 128 + tid];
        __syncthreads();
        const int c = tid & 127, kg = tid >> 7;
        const float* wp = w + (size_t)(kg * 32) * 128 + c;
        float a = 0.f;
#pragma unroll 8
        for (int k = 0; k < 32; ++k) a += xl[kg * 32 + k] * wp[(size_t)k * 128];
        ph[tid] = a;
        __syncthreads();
        if (tid < 128) hl[tid] = ph[tid] + ph[tid+128] + ph[tid+256] + ph[tid+384];
        __syncthreads();
        const float* ep = eu + (size_t)(kg * 32) * 128 + c;
        float b = 0.f;
#pragma unroll 8
        for (int k = 0; k < 32; ++k) b += hl[kg * 32 + k] * ep[(size_t)k * 128];
        ph[tid] = b;
        __syncthreads();
        if (tid < 128)
            ws[G_OFF + bid * 128 + tid] = ph[tid] + ph[tid+128] + ph[tid+256] + ph[tid+384];
        __syncthreads();
    }

    // ---- edge pass setup ----
    const int chunk = bid >> 2, q = bid & 3;
    const int dlo = q * QR;
    int drows = NN - dlo; if (drows > QR) drows = QR;
    float ajmax = -1e30f;
    for (int i = 0; i < NN; ++i) ajmax = fmaxf(ajmax, ajl[i]);
    for (int i = tid; i < QSLOTS; i += ETH) Wl[i] = 0.f;
    if (tid < QR) llast[tid] = 0.f;
    if (tid < drows) {
        float M = ail[dlo + tid] + ajmax + 1.0f;   // safe shift (softmax shift-invariant)
        Mq[tid] = (M > 0.f) ? M : NEG * M;
    }
    const float cc = atl[256];
    __syncthreads();

    // ---- edge loop ----
    const int base = chunk * CH;
    int lim = base + CH; if (lim > E) lim = E;
    const bool aligned4 = ((E & 3) == 0);
    for (int e0 = base + tid * 4; e0 < lim; e0 += ETH * 4) {
        int4 sv, dv; float4 eav;
        if (aligned4 && e0 + 3 < lim) {
            sv  = *(const int4*)(ei + e0);
            dv  = *(const int4*)(ei + E + e0);
            eav = *(const float4*)(ea + e0);
        } else {
            int e1 = lim - e0;
            sv.x = (e1 > 0) ? ei[e0]     : 0; dv.x = (e1 > 0) ? ei[E + e0]     : -1; eav.x = (e1 > 0) ? ea[e0]     : 0.f;
            sv.y = (e1 > 1) ? ei[e0 + 1] : 0; dv.y = (e1 > 1) ? ei[E + e0 + 1] : -1; eav.y = (e1 > 1) ? ea[e0 + 1] : 0.f;
            sv.z = (e1 > 2) ? ei[e0 + 2] : 0; dv.z = (e1 > 2) ? ei[E + e0 + 2] : -1; eav.z = (e1 > 2) ? ea[e0 + 2] : 0.f;
            sv.w = (e1 > 3) ? ei[e0 + 3] : 0; dv.w = (e1 > 3) ? ei[E + e0 + 3] : -1; eav.w = (e1 > 3) ? ea[e0 + 3] : 0.f;
        }
#define PROC(SS, DD, EE) do {                                   \
            int d_ = (DD) - dlo;                                \
            if ((unsigned)d_ < (unsigned)drows) {               \
                float t_ = ail[dlo + d_] + ajl[SS] + cc * (EE); \
                t_ = (t_ > 0.f) ? t_ : NEG * t_;                \
                float ev_ = __expf(t_ - Mq[d_]);                \
                atomicAdd(&Wl[d_ * NN + (SS)], ev_);            \
                atomicAdd(&llast[d_], ev_ * (EE));              \
            }                                                   \
        } while (0)
        PROC(sv.x, dv.x, eav.x);
        PROC(sv.y, dv.y, eav.y);
        PROC(sv.z, dv.z, eav.z);
        PROC(sv.w, dv.w, eav.w);
#undef PROC
    }
    __syncthreads();
    float* part = ws + PART_OFF + (size_t)bid * SL;
    for (int i = tid; i < QSLOTS; i += ETH) part[i] = Wl[i];
    if (tid < QR) part[QSLOTS + tid] = (tid < drows) ? llast[tid] : 0.f;
}

// Kernel B: fused 128-chunk reduce + wlast + rowsum + output matmul.
__global__ __launch_bounds__(ETH)
void k_outB(const float* __restrict__ ws, const float* __restrict__ eu,
            const float* __restrict__ bias, float* __restrict__ out) {
    __shared__ float wl[NN];
    __shared__ float pd[ETH];
    __shared__ float red[128];
    const int n = blockIdx.x, tid = threadIdx.x;
    const int q = n / QR, r = n % QR;
    const float* base = ws + PART_OFF + (size_t)q * SL + (size_t)r * NN;

    // W row n: sum over 128 chunks, 2-way chunk split per s
    {
        const int cg = tid >> 8, s = tid & 255;
        float acc = 0.f;
        if (s < NN) {
            const float* p = base + (size_t)(cg * 64) * (4 * SL) + s;
#pragma unroll 8
            for (int ch = 0; ch < 64; ++ch)
                acc += p[(size_t)ch * (4 * SL)];
        }
        pd[tid] = acc;
    }
    __syncthreads();
    if (tid < NN) wl[tid] = pd[tid] + pd[256 + tid];

    // wlast: one value per chunk
    if (tid < 128) red[tid] = ws[PART_OFF + (size_t)(tid * 4 + q) * SL + QSLOTS + r];
    __syncthreads();
    for (int off = 64; off > 0; off >>= 1) {
        if (tid < off) red[tid] += red[tid + off];
        __syncthreads();
    }
    const float wlast_n = red[0];
    __syncthreads();

    // rowsum (softmax denominator)
    if (tid < 128) red[tid] = wl[tid] + ((tid + 128 < NN) ? wl[tid + 128] : 0.f);
    __syncthreads();
    for (int off = 64; off > 0; off >>= 1) {
        if (tid < off) red[tid] += red[tid + off];
        __syncthreads();
    }
    const float ssum = red[0];

    // out[n][c] = (wl·G[:,c] + wlast*eu_last[c]) / ssum + bias[c]
    const float* G = ws + G_OFF;
    const int c = tid & 127, sg = tid >> 7;
    int slo = sg * 45, shi = slo + 45; if (shi > NN) shi = NN;
    float acc = 0.f;
    for (int s = slo; s < shi; ++s) acc += wl[s] * G[s * 128 + c];
    pd[tid] = acc;
    __syncthreads();
    if (tid < 128) {
        float dot = pd[tid] + pd[tid + 128] + pd[tid + 256] + pd[tid + 384];
        out[n * 128 + tid] = (dot + wlast_n * eu[128 * 128 + tid]) / (ssum + 1e-16f) + bias[tid];
    }
}

extern "C" void kernel_launch(void* const* d_in, const int* in_sizes, int n_in,
                              void* d_out, int out_size, void* d_ws, size_t ws_size,
                              hipStream_t stream) {
    const float* x     = (const float*)d_in[0];
    const float* eattr = (const float*)d_in[1];
    const float* w     = (const float*)d_in[2];
    const float* att   = (const float*)d_in[3];
    const float* eu    = (const float*)d_in[4];
    const float* bias  = (const float*)d_in[5];
    const int*   ei    = (const int*)d_in[6];
    int E = in_sizes[6] / 2;
    int CH = (((E + NCHUNK - 1) / NCHUNK) + 3) & ~3;
    float* ws = (float*)d_ws;

    k_edgeA<<<EBLOCKS, ETH, 0, stream>>>(x, eattr, w, att, eu, ei, ws, E, CH);
    k_outB<<<NN, ETH, 0, stream>>>(ws, eu, bias, (float*)d_out);
}

// Round 9
// 53.606 us; speedup vs baseline: 1.2395x; 1.2395x over previous
//
#include <hip/hip_runtime.h>

#define NN 177
#define NEG 0.2f
#define QR 45                 // dst rows per quarter (last quarter 42)
#define QSLOTS (QR * NN)      // 7965
#define SL 8064               // padded partial slice
#define NCHUNK 128
#define EBLOCKS (NCHUNK * 4)  // 512
#define ETH 512

// workspace layout (floats)
#define AI_OFF   0
#define AJ_OFF   192
#define G_OFF    384
#define PART_OFF 23040        // 512 slices of SL (~16.5 MB)

// K1: h = x@weight; ai/aj attention dots; G = h@eu. 177 blocks x 256 thr,
// split-K + 4 accumulators (proven R4/R5 structure, ~few us).
__global__ __launch_bounds__(256)
void k_node(const float* __restrict__ x, const float* __restrict__ w,
            const float* __restrict__ att, const float* __restrict__ eu,
            float* __restrict__ ws) {
    int n = blockIdx.x, tid = threadIdx.x;
    int c = tid & 127, half = tid >> 7;
    __shared__ float xl[128], hl[128], ph[256], r0[128], r1[128];
    if (tid < 128) xl[tid] = x[n * 128 + tid];
    __syncthreads();
    int k0 = half * 64;
    float a0 = 0.f, a1 = 0.f, a2 = 0.f, a3 = 0.f;
    const float* wp = w + (size_t)k0 * 128 + c;
#pragma unroll
    for (int k = 0; k < 64; k += 4) {
        a0 += xl[k0 + k]     * wp[(size_t)(k)     * 128];
        a1 += xl[k0 + k + 1] * wp[(size_t)(k + 1) * 128];
        a2 += xl[k0 + k + 2] * wp[(size_t)(k + 2) * 128];
        a3 += xl[k0 + k + 3] * wp[(size_t)(k + 3) * 128];
    }
    ph[tid] = (a0 + a1) + (a2 + a3);
    __syncthreads();
    if (half == 0) {
        float hv = ph[c] + ph[128 + c];
        hl[c] = hv;
        r0[c] = hv * att[c];
        r1[c] = hv * att[128 + c];
    }
    __syncthreads();
    for (int off = 64; off > 0; off >>= 1) {
        if (tid < off) { r0[tid] += r0[tid + off]; r1[tid] += r1[tid + off]; }
        __syncthreads();
    }
    if (tid == 0) { ws[AI_OFF + n] = r0[0]; ws[AJ_OFF + n] = r1[0]; }
    float b0 = 0.f, b1 = 0.f, b2 = 0.f, b3 = 0.f;
    const float* ep = eu + (size_t)k0 * 128 + c;
#pragma unroll
    for (int k = 0; k < 64; k += 4) {
        b0 += hl[k0 + k]     * ep[(size_t)(k)     * 128];
        b1 += hl[k0 + k + 1] * ep[(size_t)(k + 1) * 128];
        b2 += hl[k0 + k + 2] * ep[(size_t)(k + 2) * 128];
        b3 += hl[k0 + k + 3] * ep[(size_t)(k + 3) * 128];
    }
    ph[tid] = (b0 + b1) + (b2 + b3);
    __syncthreads();
    if (half == 0) ws[G_OFF + n * 128 + c] = ph[c] + ph[128 + c];
}

// K2: edge pass (proven R4/R5 structure). 2D grid (chunk, dst-quarter);
// private W-quarter in 32KB LDS; coalesced int4/float4 edge loads; partial flush.
__global__ __launch_bounds__(ETH, 8)
void k_edge(const int* __restrict__ ei, const float* __restrict__ ea,
            const float* __restrict__ att, float* __restrict__ ws, int E, int CH) {
    int chunk = blockIdx.x >> 2, q = blockIdx.x & 3;
    int dlo = q * QR;
    int drows = NN - dlo; if (drows > QR) drows = QR;
    __shared__ float Wl[QSLOTS];
    __shared__ float ajl[NN], ailq[QR], Mq[QR], llast[QR];
    int tid = threadIdx.x;
    for (int i = tid; i < QSLOTS; i += ETH) Wl[i] = 0.f;
    for (int i = tid; i < NN; i += ETH) ajl[i] = ws[AJ_OFF + i];
    if (tid < QR) llast[tid] = 0.f;
    __syncthreads();
    // safe per-dst softmax shift (softmax shift-invariant; bound avoids overflow)
    float ajmax = -1e30f;
    for (int i = 0; i < NN; ++i) ajmax = fmaxf(ajmax, ajl[i]);
    if (tid < drows) {
        float a = ws[AI_OFF + dlo + tid];
        ailq[tid] = a;
        float M = a + ajmax + 1.0f;
        Mq[tid] = (M > 0.f) ? M : NEG * M;
    }
    float cc = att[2 * 128];
    __syncthreads();

    const int base = chunk * CH;
    int lim = base + CH; if (lim > E) lim = E;
    const bool aligned4 = ((E & 3) == 0);
    for (int e0 = base + tid * 4; e0 < lim; e0 += ETH * 4) {
        int4 sv, dv; float4 eav;
        if (aligned4 && e0 + 3 < lim) {
            sv  = *(const int4*)(ei + e0);
            dv  = *(const int4*)(ei + E + e0);
            eav = *(const float4*)(ea + e0);
        } else {
            int e1 = lim - e0;
            sv.x = (e1 > 0) ? ei[e0]     : 0; dv.x = (e1 > 0) ? ei[E + e0]     : -1; eav.x = (e1 > 0) ? ea[e0]     : 0.f;
            sv.y = (e1 > 1) ? ei[e0 + 1] : 0; dv.y = (e1 > 1) ? ei[E + e0 + 1] : -1; eav.y = (e1 > 1) ? ea[e0 + 1] : 0.f;
            sv.z = (e1 > 2) ? ei[e0 + 2] : 0; dv.z = (e1 > 2) ? ei[E + e0 + 2] : -1; eav.z = (e1 > 2) ? ea[e0 + 2] : 0.f;
            sv.w = (e1 > 3) ? ei[e0 + 3] : 0; dv.w = (e1 > 3) ? ei[E + e0 + 3] : -1; eav.w = (e1 > 3) ? ea[e0 + 3] : 0.f;
        }
#define PROC(SS, DD, EE) do {                                   \
            int d_ = (DD) - dlo;                                \
            if ((unsigned)d_ < (unsigned)drows) {               \
                float t_ = ailq[d_] + ajl[SS] + cc * (EE);      \
                t_ = (t_ > 0.f) ? t_ : NEG * t_;                \
                float ev_ = __expf(t_ - Mq[d_]);                \
                atomicAdd(&Wl[d_ * NN + (SS)], ev_);            \
                atomicAdd(&llast[d_], ev_ * (EE));              \
            }                                                   \
        } while (0)
        PROC(sv.x, dv.x, eav.x);
        PROC(sv.y, dv.y, eav.y);
        PROC(sv.z, dv.z, eav.z);
        PROC(sv.w, dv.w, eav.w);
#undef PROC
    }
    __syncthreads();
    float* part = ws + PART_OFF + (size_t)blockIdx.x * SL;
    for (int i = tid; i < QSLOTS; i += ETH) part[i] = Wl[i];
    if (tid < QR) part[QSLOTS + tid] = (tid < drows) ? llast[tid] : 0.f;
}

// K3: fused 128-chunk reduce + wlast + rowsum + output matmul (proven R8).
__global__ __launch_bounds__(ETH)
void k_outB(const float* __restrict__ ws, const float* __restrict__ eu,
            const float* __restrict__ bias, float* __restrict__ out) {
    __shared__ float wl[NN];
    __shared__ float pd[ETH];
    __shared__ float red[128];
    const int n = blockIdx.x, tid = threadIdx.x;
    const int q = n / QR, r = n % QR;
    const float* base = ws + PART_OFF + (size_t)q * SL + (size_t)r * NN;

    // W row n: sum over 128 chunks, 2-way chunk split per s
    {
        const int cg = tid >> 8, s = tid & 255;
        float acc = 0.f;
        if (s < NN) {
            const float* p = base + (size_t)(cg * 64) * (4 * SL) + s;
#pragma unroll 8
            for (int ch = 0; ch < 64; ++ch)
                acc += p[(size_t)ch * (4 * SL)];
        }
        pd[tid] = acc;
    }
    __syncthreads();
    if (tid < NN) wl[tid] = pd[tid] + pd[256 + tid];

    // wlast: one value per chunk
    if (tid < 128) red[tid] = ws[PART_OFF + (size_t)(tid * 4 + q) * SL + QSLOTS + r];
    __syncthreads();
    for (int off = 64; off > 0; off >>= 1) {
        if (tid < off) red[tid] += red[tid + off];
        __syncthreads();
    }
    const float wlast_n = red[0];
    __syncthreads();

    // rowsum (softmax denominator)
    if (tid < 128) red[tid] = wl[tid] + ((tid + 128 < NN) ? wl[tid + 128] : 0.f);
    __syncthreads();
    for (int off = 64; off > 0; off >>= 1) {
        if (tid < off) red[tid] += red[tid + off];
        __syncthreads();
    }
    const float ssum = red[0];

    // out[n][c] = (wl·G[:,c] + wlast*eu_last[c]) / ssum + bias[c]
    const float* G = ws + G_OFF;
    const int c = tid & 127, sg = tid >> 7;
    int slo = sg * 45, shi = slo + 45; if (shi > NN) shi = NN;
    float acc = 0.f;
    for (int s = slo; s < shi; ++s) acc += wl[s] * G[s * 128 + c];
    pd[tid] = acc;
    __syncthreads();
    if (tid < 128) {
        float dot = pd[tid] + pd[tid + 128] + pd[tid + 256] + pd[tid + 384];
        out[n * 128 + tid] = (dot + wlast_n * eu[128 * 128 + tid]) / (ssum + 1e-16f) + bias[tid];
    }
}

extern "C" void kernel_launch(void* const* d_in, const int* in_sizes, int n_in,
                              void* d_out, int out_size, void* d_ws, size_t ws_size,
                              hipStream_t stream) {
    const float* x     = (const float*)d_in[0];
    const float* eattr = (const float*)d_in[1];
    const float* w     = (const float*)d_in[2];
    const float* att   = (const float*)d_in[3];
    const float* eu    = (const float*)d_in[4];
    const float* bias  = (const float*)d_in[5];
    const int*   ei    = (const int*)d_in[6];
    int E = in_sizes[6] / 2;
    int CH = (((E + NCHUNK - 1) / NCHUNK) + 3) & ~3;
    float* ws = (float*)d_ws;

    k_node<<<NN, 256, 0, stream>>>(x, w, att, eu, ws);
    k_edge<<<EBLOCKS, ETH, 0, stream>>>(ei, eattr, att, ws, E, CH);
    k_outB<<<NN, ETH, 0, stream>>>(ws, eu, bias, (float*)d_out);
}

// Round 10
// 41.037 us; speedup vs baseline: 1.6192x; 1.3063x over previous
//
#include <hip/hip_runtime.h>

#define NN 177
#define NEG 0.2f
#define QR 45                 // dst rows per quarter (last quarter 42)
#define QSLOTS (QR * NN)      // 7965
#define SL 8064               // padded partial slice
#define NCHUNK 64
#define EBLOCKS (NCHUNK * 4)  // 256
#define ETH 512

// workspace layout (floats)
#define AIP_OFF  0            // 354 per-(n,half) ai partials
#define AJP_OFF  384
#define H_OFF    768          // h[177][128]
#define PART_OFF 23424        // 256 slices of SL (~8.3 MB)

// K1: h = x@W, ai/aj partial dots. Grid (177, 2): block = (row n, col half).
// 4-way split-K, short chains, no G (factorized into K3).
__global__ __launch_bounds__(256)
void k_nodeH(const float* __restrict__ x, const float* __restrict__ w,
             const float* __restrict__ att, float* __restrict__ ws) {
    const int n = blockIdx.x, half = blockIdx.y;
    const int tid = threadIdx.x;
    const int j = tid & 63, kq = tid >> 6;
    __shared__ float xl[128];
    __shared__ float ph[256];
    if (tid < 128) xl[tid] = x[n * 128 + tid];
    __syncthreads();
    const float* wp = w + (size_t)(kq * 32) * 128 + half * 64 + j;
    float acc = 0.f;
#pragma unroll 8
    for (int k = 0; k < 32; ++k) acc += xl[kq * 32 + k] * wp[(size_t)k * 128];
    ph[tid] = acc;
    __syncthreads();
    if (tid < 64) {
        float hv = ph[j] + ph[64 + j] + ph[128 + j] + ph[192 + j];
        ws[H_OFF + n * 128 + half * 64 + j] = hv;
        float pa = hv * att[half * 64 + j];
        float pb = hv * att[128 + half * 64 + j];
#pragma unroll
        for (int m = 1; m < 64; m <<= 1) {
            pa += __shfl_xor(pa, m);
            pb += __shfl_xor(pb, m);
        }
        if (j == 0) {
            ws[AIP_OFF + 2 * n + half] = pa;
            ws[AJP_OFF + 2 * n + half] = pb;
        }
    }
}

// K2: edge pass (proven structure). Grid (chunk 0..63, quarter 0..3);
// private W-quarter in 32KB LDS; int4/float4 edge loads; partial flush.
__global__ __launch_bounds__(ETH, 8)
void k_edge(const int* __restrict__ ei, const float* __restrict__ ea,
            const float* __restrict__ att, float* __restrict__ ws, int E, int CH) {
    int chunk = blockIdx.x >> 2, q = blockIdx.x & 3;
    int dlo = q * QR;
    int drows = NN - dlo; if (drows > QR) drows = QR;
    __shared__ float Wl[QSLOTS];
    __shared__ float ajl[NN], ailq[QR], Mq[QR], llast[QR];
    int tid = threadIdx.x;
    for (int i = tid; i < QSLOTS; i += ETH) Wl[i] = 0.f;
    for (int i = tid; i < NN; i += ETH)
        ajl[i] = ws[AJP_OFF + 2 * i] + ws[AJP_OFF + 2 * i + 1];
    if (tid < QR) llast[tid] = 0.f;
    __syncthreads();
    // safe per-dst softmax shift (softmax shift-invariant; bound avoids overflow)
    float ajmax = -1e30f;
    for (int i = 0; i < NN; ++i) ajmax = fmaxf(ajmax, ajl[i]);
    if (tid < drows) {
        float a = ws[AIP_OFF + 2 * (dlo + tid)] + ws[AIP_OFF + 2 * (dlo + tid) + 1];
        ailq[tid] = a;
        float M = a + ajmax + 1.0f;
        Mq[tid] = (M > 0.f) ? M : NEG * M;
    }
    float cc = att[2 * 128];
    __syncthreads();

    const int base = chunk * CH;
    int lim = base + CH; if (lim > E) lim = E;
    const bool aligned4 = ((E & 3) == 0);
    for (int e0 = base + tid * 4; e0 < lim; e0 += ETH * 4) {
        int4 sv, dv; float4 eav;
        if (aligned4 && e0 + 3 < lim) {
            sv  = *(const int4*)(ei + e0);
            dv  = *(const int4*)(ei + E + e0);
            eav = *(const float4*)(ea + e0);
        } else {
            int e1 = lim - e0;
            sv.x = (e1 > 0) ? ei[e0]     : 0; dv.x = (e1 > 0) ? ei[E + e0]     : -1; eav.x = (e1 > 0) ? ea[e0]     : 0.f;
            sv.y = (e1 > 1) ? ei[e0 + 1] : 0; dv.y = (e1 > 1) ? ei[E + e0 + 1] : -1; eav.y = (e1 > 1) ? ea[e0 + 1] : 0.f;
            sv.z = (e1 > 2) ? ei[e0 + 2] : 0; dv.z = (e1 > 2) ? ei[E + e0 + 2] : -1; eav.z = (e1 > 2) ? ea[e0 + 2] : 0.f;
            sv.w = (e1 > 3) ? ei[e0 + 3] : 0; dv.w = (e1 > 3) ? ei[E + e0 + 3] : -1; eav.w = (e1 > 3) ? ea[e0 + 3] : 0.f;
        }
#define PROC(SS, DD, EE) do {                                   \
            int d_ = (DD) - dlo;                                \
            if ((unsigned)d_ < (unsigned)drows) {               \
                float t_ = ailq[d_] + ajl[SS] + cc * (EE);      \
                t_ = (t_ > 0.f) ? t_ : NEG * t_;                \
                float ev_ = __expf(t_ - Mq[d_]);                \
                atomicAdd(&Wl[d_ * NN + (SS)], ev_);            \
                atomicAdd(&llast[d_], ev_ * (EE));              \
            }                                                   \
        } while (0)
        PROC(sv.x, dv.x, eav.x);
        PROC(sv.y, dv.y, eav.y);
        PROC(sv.z, dv.z, eav.z);
        PROC(sv.w, dv.w, eav.w);
#undef PROC
    }
    __syncthreads();
    float* part = ws + PART_OFF + (size_t)blockIdx.x * SL;
    for (int i = tid; i < QSLOTS; i += ETH) part[i] = Wl[i];
    if (tid < QR) part[QSLOTS + tid] = (tid < drows) ? llast[tid] : 0.f;
}

// K3: chunk-reduce + v = W[n,:]@h (h staged in LDS, 2 passes) + out = v@eu.
__global__ __launch_bounds__(ETH)
void k_outC(const float* __restrict__ ws, const float* __restrict__ eu,
            const float* __restrict__ bias, float* __restrict__ out) {
    __shared__ float wl[NN];
    __shared__ float vl[128];
    __shared__ float red[128];
    __shared__ float sc[2];
    __shared__ float hl[89 * 128];   // 45.6 KB; also reused as pd scratch
    const int n = blockIdx.x, tid = threadIdx.x;
    const int q = n / QR, r = n % QR;

    // step 1: W row n = sum over 64 chunk-partials (2-way chunk split)
    {
        const int cg = tid >> 8, s = tid & 255;
        float acc = 0.f;
        if (s < NN) {
            const float* p = ws + PART_OFF + (size_t)q * SL + (size_t)r * NN
                           + (size_t)(cg * 32) * (4 * SL) + s;
#pragma unroll 8
            for (int ch = 0; ch < 32; ++ch)
                acc += p[(size_t)ch * (4 * SL)];
        }
        hl[tid] = acc;
    }
    // wlast partials: one per chunk
    if (tid < 64) red[tid] = ws[PART_OFF + (size_t)(tid * 4 + q) * SL + QSLOTS + r];
    __syncthreads();
    if (tid < NN) wl[tid] = hl[tid] + hl[256 + tid];
    if (tid < 32) red[tid] += red[tid + 32];
    __syncthreads();
    if (tid < 16) red[tid] += red[tid + 16];
    __syncthreads();
    if (tid < 8) red[tid] += red[tid + 8];
    __syncthreads();
    if (tid < 4) red[tid] += red[tid + 4];
    __syncthreads();
    if (tid == 0) sc[0] = (red[0] + red[1]) + (red[2] + red[3]);   // wlast_n
    __syncthreads();
    // ssum = rowsum of wl
    if (tid < 128) red[tid] = wl[tid] + ((tid + 128 < NN) ? wl[tid + 128] : 0.f);
    __syncthreads();
    for (int off = 64; off > 0; off >>= 1) {
        if (tid < off) red[tid] += red[tid + off];
        __syncthreads();
    }
    if (tid == 0) sc[1] = red[0];
    __syncthreads();

    // step 2: v[c] = sum_s wl[s] * h[s][c], h staged in LDS in 2 passes
    float vacc = 0.f;
    // pass 0: rows 0..88
    for (int i = tid; i < 89 * 128; i += ETH) hl[i] = ws[H_OFF + i];
    __syncthreads();
    if (tid < 128) {
        for (int s = 0; s < 89; ++s) vacc += wl[s] * hl[s * 128 + tid];
    }
    __syncthreads();
    // pass 1: rows 89..176
    for (int i = tid; i < 88 * 128; i += ETH) hl[i] = ws[H_OFF + 89 * 128 + i];
    __syncthreads();
    if (tid < 128) {
        for (int s = 0; s < 88; ++s) vacc += wl[89 + s] * hl[s * 128 + tid];
        vl[tid] = vacc;
    }
    __syncthreads();

    // step 3: out[n][c] = (v@eu[:,c] + wlast*eu[128][c]) / ssum + bias[c]
    {
        const int c = tid & 127, kg = tid >> 7;
        float oacc = 0.f;
        const float* ep = eu + (size_t)(kg * 32) * 128 + c;
#pragma unroll 8
        for (int k = 0; k < 32; ++k) oacc += vl[kg * 32 + k] * ep[(size_t)k * 128];
        hl[tid] = oacc;
    }
    __syncthreads();
    if (tid < 128) {
        float dot = hl[tid] + hl[128 + tid] + hl[256 + tid] + hl[384 + tid];
        out[n * 128 + tid] = (dot + sc[0] * eu[128 * 128 + tid]) / (sc[1] + 1e-16f) + bias[tid];
    }
}

extern "C" void kernel_launch(void* const* d_in, const int* in_sizes, int n_in,
                              void* d_out, int out_size, void* d_ws, size_t ws_size,
                              hipStream_t stream) {
    const float* x     = (const float*)d_in[0];
    const float* eattr = (const float*)d_in[1];
    const float* w     = (const float*)d_in[2];
    const float* att   = (const float*)d_in[3];
    const float* eu    = (const float*)d_in[4];
    const float* bias  = (const float*)d_in[5];
    const int*   ei    = (const int*)d_in[6];
    int E = in_sizes[6] / 2;
    int CH = (((E + NCHUNK - 1) / NCHUNK) + 3) & ~3;
    float* ws = (float*)d_ws;

    k_nodeH<<<dim3(NN, 2), 256, 0, stream>>>(x, w, att, ws);
    k_edge<<<EBLOCKS, ETH, 0, stream>>>(ei, eattr, att, ws, E, CH);
    k_outC<<<NN, ETH, 0, stream>>>(ws, eu, bias, (float*)d_out);
}

// Round 11
// 33.323 us; speedup vs baseline: 1.9940x; 1.2315x over previous
//
#include <hip/hip_runtime.h>

#define NN 177
#define NEG 0.2f
#define QR 45                 // dst rows per quarter (last quarter 42)
#define QSLOTS (QR * NN)      // 7965
#define SL 8064               // padded partial slice
#define NCHUNK 64
#define EBLOCKS (NCHUNK * 4)  // 256
#define ETH 512

// workspace layout (floats)
#define AIP_OFF  0            // 354 per-(n,half) ai partials
#define AJP_OFF  384
#define H_OFF    768          // h[177][128]
#define PART_OFF 23424        // 256 slices of SL (~8.3 MB)

// K1: h = x@W, ai/aj partial dots. Grid (177, 2): block = (row n, col half).
__global__ __launch_bounds__(256)
void k_nodeH(const float* __restrict__ x, const float* __restrict__ w,
             const float* __restrict__ att, float* __restrict__ ws) {
    const int n = blockIdx.x, half = blockIdx.y;
    const int tid = threadIdx.x;
    const int j = tid & 63, kq = tid >> 6;
    __shared__ float xl[128];
    __shared__ float ph[256];
    if (tid < 128) xl[tid] = x[n * 128 + tid];
    __syncthreads();
    const float* wp = w + (size_t)(kq * 32) * 128 + half * 64 + j;
    float acc = 0.f;
#pragma unroll 8
    for (int k = 0; k < 32; ++k) acc += xl[kq * 32 + k] * wp[(size_t)k * 128];
    ph[tid] = acc;
    __syncthreads();
    if (tid < 64) {
        float hv = ph[j] + ph[64 + j] + ph[128 + j] + ph[192 + j];
        ws[H_OFF + n * 128 + half * 64 + j] = hv;
        float pa = hv * att[half * 64 + j];
        float pb = hv * att[128 + half * 64 + j];
#pragma unroll
        for (int m = 1; m < 64; m <<= 1) {
            pa += __shfl_xor(pa, m);
            pb += __shfl_xor(pb, m);
        }
        if (j == 0) {
            ws[AIP_OFF + 2 * n + half] = pa;
            ws[AJP_OFF + 2 * n + half] = pb;
        }
    }
}

// K2: edge pass. XCD-swizzled grid: bid = q*NCHUNK + chunk, so the 4 blocks
// sharing a chunk are 64 apart (64%8==0 -> same XCD) and L2-share the edge
// stream. Private W-quarter in 32KB LDS; int4/float4 loads; partial flush.
__global__ __launch_bounds__(ETH, 8)
void k_edge(const int* __restrict__ ei, const float* __restrict__ ea,
            const float* __restrict__ att, float* __restrict__ ws, int E, int CH) {
    const int chunk = blockIdx.x & (NCHUNK - 1), q = blockIdx.x >> 6;
    const int dlo = q * QR;
    int drows = NN - dlo; if (drows > QR) drows = QR;
    __shared__ float Wl[QSLOTS];
    __shared__ float ajl[NN], ailq[QR], Mq[QR], llast[QR], mred[64];
    int tid = threadIdx.x;
    for (int i = tid; i < QSLOTS; i += ETH) Wl[i] = 0.f;
    for (int i = tid; i < NN; i += ETH)
        ajl[i] = ws[AJP_OFF + 2 * i] + ws[AJP_OFF + 2 * i + 1];
    if (tid < QR) llast[tid] = 0.f;
    __syncthreads();
    // parallel ajmax (was a 177-deep dependent chain per thread)
    if (tid < 64) {
        float m = -1e30f;
        for (int i = tid; i < NN; i += 64) m = fmaxf(m, ajl[i]);
        mred[tid] = m;
    }
    __syncthreads();
    if (tid < 16) mred[tid] = fmaxf(fmaxf(mred[tid], mred[tid + 16]),
                                    fmaxf(mred[tid + 32], mred[tid + 48]));
    __syncthreads();
    if (tid < 4) mred[tid] = fmaxf(fmaxf(mred[tid], mred[tid + 4]),
                                   fmaxf(mred[tid + 8], mred[tid + 12]));
    __syncthreads();
    if (tid == 0) mred[0] = fmaxf(fmaxf(mred[0], mred[1]), fmaxf(mred[2], mred[3]));
    __syncthreads();
    const float ajmax = mred[0];
    if (tid < drows) {
        float a = ws[AIP_OFF + 2 * (dlo + tid)] + ws[AIP_OFF + 2 * (dlo + tid) + 1];
        ailq[tid] = a;
        float M = a + ajmax + 1.0f;       // safe softmax shift (shift-invariant)
        Mq[tid] = (M > 0.f) ? M : NEG * M;
    }
    const float cc = att[2 * 128];
    __syncthreads();

    const int base = chunk * CH;
    int lim = base + CH; if (lim > E) lim = E;
    const bool aligned4 = ((E & 3) == 0);
    for (int e0 = base + tid * 4; e0 < lim; e0 += ETH * 4) {
        int4 sv, dv; float4 eav;
        if (aligned4 && e0 + 3 < lim) {
            sv  = *(const int4*)(ei + e0);
            dv  = *(const int4*)(ei + E + e0);
            eav = *(const float4*)(ea + e0);
        } else {
            int e1 = lim - e0;
            sv.x = (e1 > 0) ? ei[e0]     : 0; dv.x = (e1 > 0) ? ei[E + e0]     : -1; eav.x = (e1 > 0) ? ea[e0]     : 0.f;
            sv.y = (e1 > 1) ? ei[e0 + 1] : 0; dv.y = (e1 > 1) ? ei[E + e0 + 1] : -1; eav.y = (e1 > 1) ? ea[e0 + 1] : 0.f;
            sv.z = (e1 > 2) ? ei[e0 + 2] : 0; dv.z = (e1 > 2) ? ei[E + e0 + 2] : -1; eav.z = (e1 > 2) ? ea[e0 + 2] : 0.f;
            sv.w = (e1 > 3) ? ei[e0 + 3] : 0; dv.w = (e1 > 3) ? ei[E + e0 + 3] : -1; eav.w = (e1 > 3) ? ea[e0 + 3] : 0.f;
        }
#define PROC(SS, DD, EE) do {                                   \
            int d_ = (DD) - dlo;                                \
            if ((unsigned)d_ < (unsigned)drows) {               \
                float t_ = ailq[d_] + ajl[SS] + cc * (EE);      \
                t_ = (t_ > 0.f) ? t_ : NEG * t_;                \
                float ev_ = __expf(t_ - Mq[d_]);                \
                atomicAdd(&Wl[d_ * NN + (SS)], ev_);            \
                atomicAdd(&llast[d_], ev_ * (EE));              \
            }                                                   \
        } while (0)
        PROC(sv.x, dv.x, eav.x);
        PROC(sv.y, dv.y, eav.y);
        PROC(sv.z, dv.z, eav.z);
        PROC(sv.w, dv.w, eav.w);
#undef PROC
    }
    __syncthreads();
    float* part = ws + PART_OFF + (size_t)blockIdx.x * SL;
    for (int i = tid; i < QSLOTS; i += ETH) part[i] = Wl[i];
    if (tid < QR) part[QSLOTS + tid] = (tid < drows) ? llast[tid] : 0.f;
}

// K3: chunk-reduce + v = W[n,:]@h (h staged in LDS via float4) + out = v@eu.
__global__ __launch_bounds__(ETH)
void k_outC(const float* __restrict__ ws, const float* __restrict__ eu,
            const float* __restrict__ bias, float* __restrict__ out) {
    __shared__ float wl[NN];
    __shared__ float vl[128];
    __shared__ float red[128];
    __shared__ float sc[2];
    __shared__ float hl[89 * 128];   // 45.6 KB; also reused as scratch
    const int n = blockIdx.x, tid = threadIdx.x;
    const int q = n / QR, r = n % QR;
    // partial slice index for this quarter at chunk ch: (q*NCHUNK + ch)
    const size_t qbase = PART_OFF + (size_t)q * NCHUNK * SL;

    // step 1: W row n = sum over 64 chunk-partials (2-way chunk split)
    {
        const int cg = tid >> 8, s = tid & 255;
        float acc = 0.f;
        if (s < NN) {
            const float* p = ws + qbase + (size_t)(cg * 32) * SL + (size_t)r * NN + s;
#pragma unroll 8
            for (int ch = 0; ch < 32; ++ch)
                acc += p[(size_t)ch * SL];
        }
        hl[tid] = acc;
    }
    // wlast partials: one per chunk
    if (tid < 64) red[tid] = ws[qbase + (size_t)tid * SL + QSLOTS + r];
    __syncthreads();
    if (tid < NN) wl[tid] = hl[tid] + hl[256 + tid];
    if (tid < 32) red[tid] += red[tid + 32];
    __syncthreads();
    if (tid < 16) red[tid] += red[tid + 16];
    __syncthreads();
    if (tid < 8) red[tid] += red[tid + 8];
    __syncthreads();
    if (tid < 4) red[tid] += red[tid + 4];
    __syncthreads();
    if (tid == 0) sc[0] = (red[0] + red[1]) + (red[2] + red[3]);   // wlast_n
    __syncthreads();
    // ssum = rowsum of wl
    if (tid < 128) red[tid] = wl[tid] + ((tid + 128 < NN) ? wl[tid + 128] : 0.f);
    __syncthreads();
    for (int off = 64; off > 0; off >>= 1) {
        if (tid < off) red[tid] += red[tid + off];
        __syncthreads();
    }
    if (tid == 0) sc[1] = red[0];
    __syncthreads();

    // step 2: v[c] = sum_s wl[s] * h[s][c], h staged in LDS (float4) in 2 passes
    float vacc = 0.f;
    for (int i = tid; i < 89 * 32; i += ETH)
        ((float4*)hl)[i] = ((const float4*)(ws + H_OFF))[i];
    __syncthreads();
    if (tid < 128) {
        for (int s = 0; s < 89; ++s) vacc += wl[s] * hl[s * 128 + tid];
    }
    __syncthreads();
    for (int i = tid; i < 88 * 32; i += ETH)
        ((float4*)hl)[i] = ((const float4*)(ws + H_OFF + 89 * 128))[i];
    __syncthreads();
    if (tid < 128) {
        for (int s = 0; s < 88; ++s) vacc += wl[89 + s] * hl[s * 128 + tid];
        vl[tid] = vacc;
    }
    __syncthreads();

    // step 3: out[n][c] = (v@eu[:,c] + wlast*eu[128][c]) / ssum + bias[c]
    {
        const int c = tid & 127, kg = tid >> 7;
        float oacc = 0.f;
        const float* ep = eu + (size_t)(kg * 32) * 128 + c;
#pragma unroll 8
        for (int k = 0; k < 32; ++k) oacc += vl[kg * 32 + k] * ep[(size_t)k * 128];
        hl[tid] = oacc;
    }
    __syncthreads();
    if (tid < 128) {
        float dot = hl[tid] + hl[128 + tid] + hl[256 + tid] + hl[384 + tid];
        out[n * 128 + tid] = (dot + sc[0] * eu[128 * 128 + tid]) / (sc[1] + 1e-16f) + bias[tid];
    }
}

extern "C" void kernel_launch(void* const* d_in, const int* in_sizes, int n_in,
                              void* d_out, int out_size, void* d_ws, size_t ws_size,
                              hipStream_t stream) {
    const float* x     = (const float*)d_in[0];
    const float* eattr = (const float*)d_in[1];
    const float* w     = (const float*)d_in[2];
    const float* att   = (const float*)d_in[3];
    const float* eu    = (const float*)d_in[4];
    const float* bias  = (const float*)d_in[5];
    const int*   ei    = (const int*)d_in[6];
    int E = in_sizes[6] / 2;
    int CH = (((E + NCHUNK - 1) / NCHUNK) + 3) & ~3;
    float* ws = (float*)d_ws;

    k_nodeH<<<dim3(NN, 2), 256, 0, stream>>>(x, w, att, ws);
    k_edge<<<EBLOCKS, ETH, 0, stream>>>(ei, eattr, att, ws, E, CH);
    k_outC<<<NN, ETH, 0, stream>>>(ws, eu, bias, (float*)d_out);
}

// Round 12
// 32.385 us; speedup vs baseline: 2.0517x; 1.0290x over previous
//
#include <hip/hip_runtime.h>

#define NN 177
#define NEG 0.2f
#define QR 45                 // dst rows per quarter (last quarter 42)
#define ROWP 180              // padded W row stride (16B-aligned float4)
#define QSLOTS_P (QR * ROWP)  // 8100
#define SL 8192               // partial slice stride (floats, 32KB)
#define NCHUNK 64
#define EBLOCKS (NCHUNK * 4)  // 256
#define ETH 512

// workspace layout (floats)
#define AIP_OFF  0            // 354 per-(n,half) ai partials
#define AJP_OFF  384
#define H_OFF    768          // h[177][128]
#define PART_OFF 23424        // 256 slices of SL (~8.4 MB), 16B aligned

__device__ __forceinline__ float4 f4add(float4 a, float4 b) {
    return make_float4(a.x + b.x, a.y + b.y, a.z + b.z, a.w + b.w);
}

// K1: h = x@W, ai/aj partial dots. Grid (177, 2): block = (row n, col half).
__global__ __launch_bounds__(256)
void k_nodeH(const float* __restrict__ x, const float* __restrict__ w,
             const float* __restrict__ att, float* __restrict__ ws) {
    const int n = blockIdx.x, half = blockIdx.y;
    const int tid = threadIdx.x;
    const int j = tid & 63, kq = tid >> 6;
    __shared__ float xl[128];
    __shared__ float ph[256];
    if (tid < 128) xl[tid] = x[n * 128 + tid];
    __syncthreads();
    const float* wp = w + (size_t)(kq * 32) * 128 + half * 64 + j;
    float acc = 0.f;
#pragma unroll 8
    for (int k = 0; k < 32; ++k) acc += xl[kq * 32 + k] * wp[(size_t)k * 128];
    ph[tid] = acc;
    __syncthreads();
    if (tid < 64) {
        float hv = ph[j] + ph[64 + j] + ph[128 + j] + ph[192 + j];
        ws[H_OFF + n * 128 + half * 64 + j] = hv;
        float pa = hv * att[half * 64 + j];
        float pb = hv * att[128 + half * 64 + j];
#pragma unroll
        for (int m = 1; m < 64; m <<= 1) {
            pa += __shfl_xor(pa, m);
            pb += __shfl_xor(pb, m);
        }
        if (j == 0) {
            ws[AIP_OFF + 2 * n + half] = pa;
            ws[AJP_OFF + 2 * n + half] = pb;
        }
    }
}

// K2: edge pass. XCD-swizzled grid: bid = q*NCHUNK + chunk (64%8==0 -> the 4
// quarter-blocks of a chunk share an XCD L2). Stride-180 LDS tile, float4
// zero-init + flush. int4/float4 edge loads.
__global__ __launch_bounds__(ETH, 8)
void k_edge(const int* __restrict__ ei, const float* __restrict__ ea,
            const float* __restrict__ att, float* __restrict__ ws, int E, int CH) {
    const int chunk = blockIdx.x & (NCHUNK - 1), q = blockIdx.x >> 6;
    const int dlo = q * QR;
    int drows = NN - dlo; if (drows > QR) drows = QR;
    __shared__ __align__(16) float Wl[QSLOTS_P];
    __shared__ float ajl[NN], ailq[QR], Mq[QR], llast[QR], mred[64];
    int tid = threadIdx.x;
    const float4 z4 = make_float4(0.f, 0.f, 0.f, 0.f);
    for (int i = tid; i < QSLOTS_P / 4; i += ETH) ((float4*)Wl)[i] = z4;
    for (int i = tid; i < NN; i += ETH)
        ajl[i] = ws[AJP_OFF + 2 * i] + ws[AJP_OFF + 2 * i + 1];
    if (tid < QR) llast[tid] = 0.f;
    __syncthreads();
    // parallel ajmax
    if (tid < 64) {
        float m = -1e30f;
        for (int i = tid; i < NN; i += 64) m = fmaxf(m, ajl[i]);
        mred[tid] = m;
    }
    __syncthreads();
    if (tid < 16) mred[tid] = fmaxf(fmaxf(mred[tid], mred[tid + 16]),
                                    fmaxf(mred[tid + 32], mred[tid + 48]));
    __syncthreads();
    if (tid < 4) mred[tid] = fmaxf(fmaxf(mred[tid], mred[tid + 4]),
                                   fmaxf(mred[tid + 8], mred[tid + 12]));
    __syncthreads();
    if (tid == 0) mred[0] = fmaxf(fmaxf(mred[0], mred[1]), fmaxf(mred[2], mred[3]));
    __syncthreads();
    const float ajmax = mred[0];
    if (tid < drows) {
        float a = ws[AIP_OFF + 2 * (dlo + tid)] + ws[AIP_OFF + 2 * (dlo + tid) + 1];
        ailq[tid] = a;
        float M = a + ajmax + 1.0f;       // safe softmax shift (shift-invariant)
        Mq[tid] = (M > 0.f) ? M : NEG * M;
    }
    const float cc = att[2 * 128];
    __syncthreads();

    const int base = chunk * CH;
    int lim = base + CH; if (lim > E) lim = E;
    const bool aligned4 = ((E & 3) == 0);
    for (int e0 = base + tid * 4; e0 < lim; e0 += ETH * 4) {
        int4 sv, dv; float4 eav;
        if (aligned4 && e0 + 3 < lim) {
            sv  = *(const int4*)(ei + e0);
            dv  = *(const int4*)(ei + E + e0);
            eav = *(const float4*)(ea + e0);
        } else {
            int e1 = lim - e0;
            sv.x = (e1 > 0) ? ei[e0]     : 0; dv.x = (e1 > 0) ? ei[E + e0]     : -1; eav.x = (e1 > 0) ? ea[e0]     : 0.f;
            sv.y = (e1 > 1) ? ei[e0 + 1] : 0; dv.y = (e1 > 1) ? ei[E + e0 + 1] : -1; eav.y = (e1 > 1) ? ea[e0 + 1] : 0.f;
            sv.z = (e1 > 2) ? ei[e0 + 2] : 0; dv.z = (e1 > 2) ? ei[E + e0 + 2] : -1; eav.z = (e1 > 2) ? ea[e0 + 2] : 0.f;
            sv.w = (e1 > 3) ? ei[e0 + 3] : 0; dv.w = (e1 > 3) ? ei[E + e0 + 3] : -1; eav.w = (e1 > 3) ? ea[e0 + 3] : 0.f;
        }
#define PROC(SS, DD, EE) do {                                   \
            int d_ = (DD) - dlo;                                \
            if ((unsigned)d_ < (unsigned)drows) {               \
                float t_ = ailq[d_] + ajl[SS] + cc * (EE);      \
                t_ = (t_ > 0.f) ? t_ : NEG * t_;                \
                float ev_ = __expf(t_ - Mq[d_]);                \
                atomicAdd(&Wl[d_ * ROWP + (SS)], ev_);          \
                atomicAdd(&llast[d_], ev_ * (EE));              \
            }                                                   \
        } while (0)
        PROC(sv.x, dv.x, eav.x);
        PROC(sv.y, dv.y, eav.y);
        PROC(sv.z, dv.z, eav.z);
        PROC(sv.w, dv.w, eav.w);
#undef PROC
    }
    __syncthreads();
    float* part = ws + PART_OFF + (size_t)blockIdx.x * SL;
    for (int i = tid; i < QSLOTS_P / 4; i += ETH)
        ((float4*)part)[i] = ((const float4*)Wl)[i];
    if (tid < QR) part[QSLOTS_P + tid] = llast[tid];
}

// K3: float4 chunk-reduce (8-way) + 4-way-split v = W[n,:]@h + out = v@eu.
__global__ __launch_bounds__(ETH)
void k_outC(const float* __restrict__ ws, const float* __restrict__ eu,
            const float* __restrict__ bias, float* __restrict__ out) {
    __shared__ __align__(16) float wl[ROWP];
    __shared__ float vl[128];
    __shared__ float red[128];
    __shared__ float sc[2];
    __shared__ __align__(16) float hl[89 * 128];   // 45.6 KB
    __shared__ __align__(16) float pd[2048];       // 8 KB scratch (512 float4)
    const int n = blockIdx.x, tid = threadIdx.x;
    const int q = n / QR, r = n % QR;
    const size_t qbase = PART_OFF + (size_t)q * NCHUNK * SL;

    // step 1: W row n = float4 sum over 64 chunks, 8-way chunk-group split
    {
        const int lane = tid & 63, cg = tid >> 6;   // cg 0..7
        const int s4 = lane * 4;
        float4 acc = make_float4(0.f, 0.f, 0.f, 0.f);
        if (s4 < ROWP) {        // lanes 0..44
            const float* p = ws + qbase + (size_t)(cg * 8) * SL + (size_t)r * ROWP + s4;
#pragma unroll
            for (int ch = 0; ch < 8; ++ch)
                acc = f4add(acc, *(const float4*)(p + (size_t)ch * SL));
        }
        ((float4*)pd)[tid] = acc;
    }
    // wlast partials: one per chunk
    if (tid < 64) red[tid] = ws[qbase + (size_t)tid * SL + QSLOTS_P + r];
    __syncthreads();
    if (tid < 256) ((float4*)pd)[tid] = f4add(((float4*)pd)[tid], ((float4*)pd)[tid + 256]);
    if (tid < 32) red[tid] += red[tid + 32];
    __syncthreads();
    if (tid < 128) ((float4*)pd)[tid] = f4add(((float4*)pd)[tid], ((float4*)pd)[tid + 128]);
    if (tid < 16) red[tid] += red[tid + 16];
    __syncthreads();
    if (tid < 64) {
        float4 v = f4add(((float4*)pd)[tid], ((float4*)pd)[tid + 64]);
        if (tid * 4 < ROWP) ((float4*)wl)[tid] = v;
    }
    if (tid < 8) red[tid] += red[tid + 8];
    __syncthreads();
    if (tid == 0) {
        float wv = 0.f;
#pragma unroll
        for (int i = 0; i < 8; ++i) wv += red[i];
        sc[0] = wv;                                  // wlast_n
    }
    __syncthreads();
    // ssum = rowsum of wl[0..176]  (pads 177..179 are zero by construction)
    if (tid < 128) red[tid] = wl[tid] + ((tid + 128 < NN) ? wl[tid + 128] : 0.f);
    __syncthreads();
    for (int off = 64; off > 0; off >>= 1) {
        if (tid < off) red[tid] += red[tid + off];
        __syncthreads();
    }
    if (tid == 0) sc[1] = red[0];

    // step 2: v[c] = sum_s wl[s]*h[s][c]; 4-way s-split, 2 LDS passes of h
    const int c = tid & 127, g = tid >> 7;           // g 0..3
    float vacc = 0.f;
    __syncthreads();
    for (int i = tid; i < 89 * 32; i += ETH)
        ((float4*)hl)[i] = ((const float4*)(ws + H_OFF))[i];
    __syncthreads();
    {
        int s0 = (g * 89) >> 2, s1 = ((g + 1) * 89) >> 2;
        for (int s = s0; s < s1; ++s) vacc += wl[s] * hl[s * 128 + c];
    }
    __syncthreads();
    for (int i = tid; i < 88 * 32; i += ETH)
        ((float4*)hl)[i] = ((const float4*)(ws + H_OFF + 89 * 128))[i];
    __syncthreads();
    {
        int s0 = (g * 88) >> 2, s1 = ((g + 1) * 88) >> 2;
        for (int s = s0; s < s1; ++s) vacc += wl[89 + s] * hl[s * 128 + c];
    }
    pd[tid] = vacc;
    __syncthreads();
    if (tid < 128) vl[tid] = (pd[tid] + pd[128 + tid]) + (pd[256 + tid] + pd[384 + tid]);
    __syncthreads();

    // step 3: out[n][c] = (v@eu[:,c] + wlast*eu[128][c]) / ssum + bias[c]
    {
        const int kg = tid >> 7;
        float oacc = 0.f;
        const float* ep = eu + (size_t)(kg * 32) * 128 + c;
#pragma unroll 8
        for (int k = 0; k < 32; ++k) oacc += vl[kg * 32 + k] * ep[(size_t)k * 128];
        pd[tid] = oacc;
    }
    __syncthreads();
    if (tid < 128) {
        float dot = (pd[tid] + pd[128 + tid]) + (pd[256 + tid] + pd[384 + tid]);
        out[n * 128 + tid] = (dot + sc[0] * eu[128 * 128 + tid]) / (sc[1] + 1e-16f) + bias[tid];
    }
}

extern "C" void kernel_launch(void* const* d_in, const int* in_sizes, int n_in,
                              void* d_out, int out_size, void* d_ws, size_t ws_size,
                              hipStream_t stream) {
    const float* x     = (const float*)d_in[0];
    const float* eattr = (const float*)d_in[1];
    const float* w     = (const float*)d_in[2];
    const float* att   = (const float*)d_in[3];
    const float* eu    = (const float*)d_in[4];
    const float* bias  = (const float*)d_in[5];
    const int*   ei    = (const int*)d_in[6];
    int E = in_sizes[6] / 2;
    int CH = (((E + NCHUNK - 1) / NCHUNK) + 3) & ~3;
    float* ws = (float*)d_ws;

    k_nodeH<<<dim3(NN, 2), 256, 0, stream>>>(x, w, att, ws);
    k_edge<<<EBLOCKS, ETH, 0, stream>>>(ei, eattr, att, ws, E, CH);
    k_outC<<<NN, ETH, 0, stream>>>(ws, eu, bias, (float*)d_out);
}